// Round 5
// baseline (231.640 us; speedup 1.0000x reference)
//
#include <hip/hip_runtime.h>
#include <hip/hip_bf16.h>

#define NROWS 8192
#define DIM   1024
#define OUTD  1024
#define NE    16
#define BM    128
#define BN    64
#define BK    32
#define MAXT  96
#define NKSTEP (DIM / BK)   // 32
#define NTILE  (OUTD / BN)  // 16
#define GATEBLKS 512
#define CONVBLKS 2048

typedef short s16x8 __attribute__((ext_vector_type(8)));
typedef float f32x4 __attribute__((ext_vector_type(4)));

__device__ __forceinline__ unsigned f2bf(float f) {
  __hip_bfloat16 h = __float2bfloat16(f);
  return (unsigned)__builtin_bit_cast(unsigned short, h);
}

__device__ __forceinline__ void gload_lds16(const void* g, void* l) {
  __builtin_amdgcn_global_load_lds(
      (const __attribute__((address_space(1))) void*)g,
      (__attribute__((address_space(3))) void*)l, 16, 0, 0);
}

// ------- fused: gate (blocks 0..511) + We fp32->bf16 convert (512..2559) ----
// gate: full-D fp32 logits (Wg in 64KB LDS), butterfly reduce, softmax,
// argmax, fused x->bf16 conversion, per-block expert histogram (no atomics).
__global__ __launch_bounds__(256) void gate_conv_kernel(
    const float* __restrict__ x, const float* __restrict__ Wg,
    const float* __restrict__ We,
    float* __restrict__ gate_out, int* __restrict__ eid,
    float* __restrict__ wsel, ushort* __restrict__ xb,
    ushort* __restrict__ Web, int* __restrict__ hist_g)
{
  __shared__ __align__(16) float4 wg4[NE * 256];  // 64 KB fp32 Wg
  __shared__ int hist[NE];
  int t = threadIdx.x;

  if (blockIdx.x >= GATEBLKS) {
    // ---- convert path: 2048 blocks x 256 thr x 32 elems ----
    int b = blockIdx.x - GATEBLKS;
    size_t base = ((size_t)b * 256 + t) * 8;
    #pragma unroll
    for (int i = 0; i < 4; ++i) {
      size_t idx = base + (size_t)i * ((size_t)CONVBLKS * 256 * 8);
      float4 a = *(const float4*)(We + idx);
      float4 c = *(const float4*)(We + idx + 4);
      unsigned w0 = f2bf(a.x) | (f2bf(a.y) << 16);
      unsigned w1 = f2bf(a.z) | (f2bf(a.w) << 16);
      unsigned w2 = f2bf(c.x) | (f2bf(c.y) << 16);
      unsigned w3 = f2bf(c.z) | (f2bf(c.w) << 16);
      *(uint4*)(Web + idx) = make_uint4(w0, w1, w2, w3);
    }
    return;
  }

  // ---- gate path ----
  int wid = t >> 6, lane = t & 63;
  if (t < NE) hist[t] = 0;
  const float4* wgg = (const float4*)Wg;
  #pragma unroll
  for (int i = 0; i < 16; ++i) wg4[t + i * 256] = wgg[t + i * 256];
  __syncthreads();

  int n0 = blockIdx.x * 16 + wid * 4;

  float acc[4][NE];
  #pragma unroll
  for (int r = 0; r < 4; ++r)
    #pragma unroll
    for (int e = 0; e < NE; ++e) acc[r][e] = 0.f;

  #pragma unroll
  for (int j = 0; j < 4; ++j) {
    float4 xv[4];
    #pragma unroll
    for (int r = 0; r < 4; ++r) {
      xv[r] = *(const float4*)(x + (size_t)(n0 + r) * DIM + j * 256 + 4 * lane);
      unsigned lo = f2bf(xv[r].x) | (f2bf(xv[r].y) << 16);
      unsigned hi = f2bf(xv[r].z) | (f2bf(xv[r].w) << 16);
      *(uint2*)(xb + (size_t)(n0 + r) * DIM + j * 256 + 4 * lane) = make_uint2(lo, hi);
    }
    #pragma unroll
    for (int e = 0; e < NE; ++e) {
      float4 w = wg4[e * 256 + j * 64 + lane];
      #pragma unroll
      for (int r = 0; r < 4; ++r)
        acc[r][e] += xv[r].x * w.x + xv[r].y * w.y + xv[r].z * w.z + xv[r].w * w.w;
    }
  }

  #pragma unroll
  for (int r = 0; r < 4; ++r) {
    int n = n0 + r;
    float v[NE];
    #pragma unroll
    for (int e = 0; e < NE; ++e) v[e] = acc[r][e];
    #pragma unroll
    for (int i = 0; i < 8; ++i) {
      float send = (lane & 32) ? v[i] : v[i + 8];
      float recv = __shfl_xor(send, 32, 64);
      v[i] = ((lane & 32) ? v[i + 8] : v[i]) + recv;
    }
    #pragma unroll
    for (int i = 0; i < 4; ++i) {
      float send = (lane & 16) ? v[i] : v[i + 4];
      float recv = __shfl_xor(send, 16, 64);
      v[i] = ((lane & 16) ? v[i + 4] : v[i]) + recv;
    }
    #pragma unroll
    for (int i = 0; i < 2; ++i) {
      float send = (lane & 8) ? v[i] : v[i + 2];
      float recv = __shfl_xor(send, 8, 64);
      v[i] = ((lane & 8) ? v[i + 2] : v[i]) + recv;
    }
    {
      float send = (lane & 4) ? v[0] : v[1];
      float recv = __shfl_xor(send, 4, 64);
      v[0] = ((lane & 4) ? v[1] : v[0]) + recv;
    }
    v[0] += __shfl_xor(v[0], 2, 64);
    v[0] += __shfl_xor(v[0], 1, 64);
    float lg = v[0];
    int e = ((lane >> 5) & 1) * 8 + ((lane >> 4) & 1) * 4 +
            ((lane >> 3) & 1) * 2 + ((lane >> 2) & 1);
    float m = lg;
    m = fmaxf(m, __shfl_xor(m, 4, 64));
    m = fmaxf(m, __shfl_xor(m, 8, 64));
    m = fmaxf(m, __shfl_xor(m, 16, 64));
    m = fmaxf(m, __shfl_xor(m, 32, 64));
    float p = expf(lg - m);
    float s = p;
    s += __shfl_xor(s, 4, 64);
    s += __shfl_xor(s, 8, 64);
    s += __shfl_xor(s, 16, 64);
    s += __shfl_xor(s, 32, 64);
    float inv = 1.f / s;
    if ((lane & 3) == 0) gate_out[(size_t)n * NE + e] = p * inv;
    unsigned long long msk = __ballot(lg == m);
    if (lane == 0) {
      int fl = __builtin_ctzll(msk);
      int ebest = ((fl >> 5) & 1) * 8 + ((fl >> 4) & 1) * 4 +
                  ((fl >> 3) & 1) * 2 + ((fl >> 2) & 1);
      eid[n] = ebest;
      wsel[n] = inv;
      atomicAdd(&hist[ebest], 1);
    }
  }
  __syncthreads();
  if (t < NE) hist_g[blockIdx.x * NE + t] = hist[t];
}

// ---------------- plan: reduce hists, prefix, tiles, cursors ----------------
__global__ __launch_bounds__(256) void plan_kernel(
    const int* __restrict__ hist_g, int* __restrict__ offsets,
    int* __restrict__ cursors, int4* __restrict__ tiles)
{
  __shared__ int part[16][17];
  __shared__ int sh_total;
  int t = threadIdx.x;
  int e = t & 15, chunk = t >> 4;
  int s = 0;
  #pragma unroll
  for (int i = 0; i < 32; ++i) s += hist_g[(chunk * 32 + i) * NE + e];
  part[chunk][e] = s;
  __syncthreads();
  if (t < 64) {
    int lane = t;
    int c = 0;
    if (lane < NE) {
      #pragma unroll
      for (int ch = 0; ch < 16; ++ch) c += part[ch][lane];
    }
    int nt = (c + BM - 1) >> 7;
    int po = c, pt = nt;
    #pragma unroll
    for (int d = 1; d < 16; d <<= 1) {
      int oc = __shfl_up(po, d, 64);
      int ot = __shfl_up(pt, d, 64);
      if (lane >= d) { po += oc; pt += ot; }
    }
    int off = po - c, tbase = pt - nt;
    if (lane < NE) { offsets[lane] = off; cursors[lane] = off; }
    if (lane == NE - 1) { offsets[NE] = po; sh_total = pt; }
    if (lane < NE) {
      int ti = 0;
      for (int m = 0; m < c; m += BM, ++ti)
        tiles[tbase + ti] = make_int4(lane, off + m, (c - m < BM) ? (c - m) : BM, 0);
    }
  }
  __syncthreads();
  for (int i = sh_total + t; i < MAXT; i += 256)
    tiles[i] = make_int4(-1, 0, 0, 0);
}

// ---------------- scatter rows by expert (cursors pre-seeded = offsets) ----
__global__ __launch_bounds__(256) void scatter_kernel(
    const int* __restrict__ eid, int* __restrict__ cursors,
    int* __restrict__ rowids)
{
  __shared__ int h[NE];
  __shared__ int base[NE];
  int t = threadIdx.x;
  if (t < NE) h[t] = 0;
  __syncthreads();
  int n = blockIdx.x * 256 + t;
  int e = eid[n];
  int local = atomicAdd(&h[e], 1);
  __syncthreads();
  if (t < NE) base[t] = h[t] ? atomicAdd(&cursors[t], h[t]) : 0;
  __syncthreads();
  rowids[base[e] + local] = n;
}

// ------- gathered per-expert GEMM, bf16, DEPTH-3 counted-vmcnt pipeline ----
// LDS per buffer: A 8KB (128 rows x 64B) + B 4KB (64 rows x 64B), 3 buffers.
// Slot swizzle: phys slot = cg ^ ((row>>1)&3); DMA dest linear, source
// pre-swizzled; ds_read applies same XOR -> 2-way max (free).
__global__ __launch_bounds__(256, 4) void moe_gemm_kernel(
    const ushort* __restrict__ xb, const ushort* __restrict__ Web,
    const float* __restrict__ be, const int* __restrict__ rowids,
    const float* __restrict__ wsel, const int4* __restrict__ tiles,
    float* __restrict__ out)
{
  __shared__ __align__(16) char lds[3 * 12288];   // 36 KB ring
  __shared__ int   rows_s[BM];
  __shared__ float w_s[BM];

  int4 ti = tiles[blockIdx.x];
  int e = ti.x;
  if (e < 0) return;
  int srow = ti.y, nvalid = ti.z;
  int t = threadIdx.x, lane = t & 63;
  int wid = t >> 6, wm = wid >> 1, wn = wid & 1;
  int ncol0 = blockIdx.y * BN;

  if (t < BM) {
    int valid = t < nvalid;
    int rid = valid ? rowids[srow + t] : 0;
    rows_s[t] = valid ? rid : -1;
    w_s[t] = valid ? wsel[rid] : 0.f;
  }

  // staging geometry: thread t -> A rows r1=t>>2, r1+64; B row r1; slot t&3
  int r1 = t >> 2, sl = t & 3;
  int r2 = r1 + 64;
  int cg = sl ^ ((r1 >> 1) & 3);
  int rida1 = (r1 < nvalid) ? rowids[srow + r1] : 0;
  int rida2 = (r2 < nvalid) ? rowids[srow + r2] : 0;
  const ushort* ap1 = xb + (size_t)rida1 * DIM + cg * 8;
  const ushort* ap2 = xb + (size_t)rida2 * DIM + cg * 8;
  const ushort* bp1 = Web + (size_t)e * OUTD * DIM + (size_t)(ncol0 + r1) * DIM + cg * 8;

  f32x4 zero = {0.f, 0.f, 0.f, 0.f};
  f32x4 acc[4][2];
  #pragma unroll
  for (int i = 0; i < 4; ++i)
    #pragma unroll
    for (int j = 0; j < 2; ++j) acc[i][j] = zero;

  auto stage = [&](int bufoff, int koff) {
    char* A = lds + bufoff;
    char* B = A + 8192;
    gload_lds16(ap1 + koff, A + t * 16);
    gload_lds16(ap2 + koff, A + 4096 + t * 16);
    gload_lds16(bp1 + koff, B + t * 16);
  };

  unsigned rl15 = lane & 15, rcg = lane >> 4;
  auto body = [&](int bufoff) {
    const char* A = lds + bufoff;
    const char* B = A + 8192;
    s16x8 af[4], bf_[2];
    #pragma unroll
    for (int f = 0; f < 4; ++f) {
      unsigned rA = wm * 64 + f * 16 + rl15;
      af[f] = *(const s16x8*)(A + rA * 64 + ((rcg ^ ((rA >> 1) & 3)) * 16));
    }
    #pragma unroll
    for (int f = 0; f < 2; ++f) {
      unsigned rB = wn * 32 + f * 16 + rl15;
      bf_[f] = *(const s16x8*)(B + rB * 64 + ((rcg ^ ((rB >> 1) & 3)) * 16));
    }
    #pragma unroll
    for (int fm = 0; fm < 4; ++fm)
      #pragma unroll
      for (int fn = 0; fn < 2; ++fn)
        acc[fm][fn] = __builtin_amdgcn_mfma_f32_16x16x32_bf16(af[fm], bf_[fn], acc[fm][fn], 0, 0, 0);
  };

  // drain setup loads so vmcnt accounting below is exact
  asm volatile("s_waitcnt vmcnt(0)" ::: "memory");
  stage(0, 0);
  stage(12288, BK);
  int stg = 24576, cur = 0;

  for (int ks = 0; ks < NKSTEP - 1; ++ks) {
    asm volatile("s_waitcnt vmcnt(3)" ::: "memory");   // cur buffer's 3 DMAs done
    __builtin_amdgcn_s_barrier();                      // all waves' DMAs done,
    asm volatile("" ::: "memory");                     // prior readers finished
    if (ks < NKSTEP - 2) {
      stage(stg, (ks + 2) * BK);
      stg = (stg == 24576) ? 0 : stg + 12288;
    }
    body(cur);
    cur = (cur == 24576) ? 0 : cur + 12288;
  }
  asm volatile("s_waitcnt vmcnt(0)" ::: "memory");
  __builtin_amdgcn_s_barrier();
  asm volatile("" ::: "memory");
  body(cur);

  // epilogue: out[row][col] = w * (acc + be[e][col])
  int rgrp = lane >> 4;
  #pragma unroll
  for (int fn = 0; fn < 2; ++fn) {
    int col = ncol0 + wn * 32 + fn * 16 + (lane & 15);
    float bev = be[e * OUTD + col];
    #pragma unroll
    for (int fm = 0; fm < 4; ++fm) {
      #pragma unroll
      for (int j = 0; j < 4; ++j) {
        int rl = wm * 64 + fm * 16 + rgrp * 4 + j;
        int orow = rows_s[rl];
        if (orow >= 0) {
          float w = w_s[rl];
          out[(size_t)orow * OUTD + col] = w * (acc[fm][fn][j] + bev);
        }
      }
    }
  }
}

extern "C" void kernel_launch(void* const* d_in, const int* in_sizes, int n_in,
                              void* d_out, int out_size, void* d_ws, size_t ws_size,
                              hipStream_t stream) {
  const float* x  = (const float*)d_in[0];
  const float* Wg = (const float*)d_in[1];
  const float* We = (const float*)d_in[2];
  const float* be = (const float*)d_in[3];
  float* out = (float*)d_out;
  float* gate_out = out + (size_t)NROWS * OUTD;

  char* ws = (char*)d_ws;
  int*  cursors = (int*)ws;                        // 16 @ 0
  int*  offsets = (int*)(ws + 64);                 // 17 @ 64
  int4* tiles   = (int4*)(ws + 256);               // 96*16 B
  int*  hist_g  = (int*)(ws + 4096);               // 512*16*4 = 32 KB
  int*  eidp    = (int*)(ws + 40960);              // 32 KB
  float* wselp  = (float*)(ws + 40960 + 4 * NROWS);
  int*  rowids  = (int*)(ws + 40960 + 8 * NROWS);
  ushort* xb    = (ushort*)(ws + (1u << 20));                  // 16 MB
  ushort* Web   = (ushort*)(ws + (1u << 20) + 16777216u);      // 32 MB

  hipLaunchKernelGGL(gate_conv_kernel, dim3(GATEBLKS + CONVBLKS), dim3(256), 0, stream,
                     x, Wg, We, gate_out, eidp, wselp, xb, Web, hist_g);
  hipLaunchKernelGGL(plan_kernel, dim3(1), dim3(256), 0, stream,
                     hist_g, offsets, cursors, tiles);
  hipLaunchKernelGGL(scatter_kernel, dim3(NROWS / 256), dim3(256), 0, stream,
                     eidp, cursors, rowids);
  hipLaunchKernelGGL(moe_gemm_kernel, dim3(MAXT, NTILE), dim3(256), 0, stream,
                     xb, Web, be, rowids, wselp, tiles, out);
}

// Round 6
// 231.472 us; speedup vs baseline: 1.0007x; 1.0007x over previous
//
#include <hip/hip_runtime.h>
#include <hip/hip_bf16.h>

#define NROWS 8192
#define DIM   1024
#define OUTD  1024
#define NE    16
#define BM    128
#define BN    64
#define BK    32
#define MAXT  96
#define NKSTEP (DIM / BK)   // 32
#define NTILE  (OUTD / BN)  // 16
#define GATEBLKS 512
#define CONVBLKS 2048

typedef short s16x8 __attribute__((ext_vector_type(8)));
typedef float f32x4 __attribute__((ext_vector_type(4)));

__device__ __forceinline__ unsigned f2bf(float f) {
  __hip_bfloat16 h = __float2bfloat16(f);
  return (unsigned)__builtin_bit_cast(unsigned short, h);
}

__device__ __forceinline__ void gload_lds16(const void* g, void* l) {
  __builtin_amdgcn_global_load_lds(
      (const __attribute__((address_space(1))) void*)g,
      (__attribute__((address_space(3))) void*)l, 16, 0, 0);
}

// ---------------- We fp32 -> bf16 (no LDS, full occupancy) ----------------
__global__ __launch_bounds__(256) void convert_we_kernel(
    const float* __restrict__ W, ushort* __restrict__ o) {
  size_t base = ((size_t)blockIdx.x * 256 + threadIdx.x) * 8;
  #pragma unroll
  for (int i = 0; i < 4; ++i) {
    size_t idx = base + (size_t)i * ((size_t)CONVBLKS * 256 * 8);
    float4 a = *(const float4*)(W + idx);
    float4 c = *(const float4*)(W + idx + 4);
    unsigned w0 = f2bf(a.x) | (f2bf(a.y) << 16);
    unsigned w1 = f2bf(a.z) | (f2bf(a.w) << 16);
    unsigned w2 = f2bf(c.x) | (f2bf(c.y) << 16);
    unsigned w3 = f2bf(c.z) | (f2bf(c.w) << 16);
    *(uint4*)(o + idx) = make_uint4(w0, w1, w2, w3);
  }
}

// ------- gate: full-D fp32 logits (Wg in 64KB LDS), butterfly reduce,
// ------- softmax, argmax, fused x->bf16 conversion, per-block histogram ----
__global__ __launch_bounds__(256) void gate_kernel(
    const float* __restrict__ x, const float* __restrict__ Wg,
    float* __restrict__ gate_out, int* __restrict__ eid,
    float* __restrict__ wsel, ushort* __restrict__ xb,
    int* __restrict__ hist_g)
{
  __shared__ __align__(16) float4 wg4[NE * 256];  // 64 KB fp32 Wg
  __shared__ int hist[NE];
  int t = threadIdx.x;
  int wid = t >> 6, lane = t & 63;
  if (t < NE) hist[t] = 0;
  const float4* wgg = (const float4*)Wg;
  #pragma unroll
  for (int i = 0; i < 16; ++i) wg4[t + i * 256] = wgg[t + i * 256];
  __syncthreads();

  int n0 = blockIdx.x * 16 + wid * 4;

  float acc[4][NE];
  #pragma unroll
  for (int r = 0; r < 4; ++r)
    #pragma unroll
    for (int e = 0; e < NE; ++e) acc[r][e] = 0.f;

  #pragma unroll
  for (int j = 0; j < 4; ++j) {
    float4 xv[4];
    #pragma unroll
    for (int r = 0; r < 4; ++r) {
      xv[r] = *(const float4*)(x + (size_t)(n0 + r) * DIM + j * 256 + 4 * lane);
      unsigned lo = f2bf(xv[r].x) | (f2bf(xv[r].y) << 16);
      unsigned hi = f2bf(xv[r].z) | (f2bf(xv[r].w) << 16);
      *(uint2*)(xb + (size_t)(n0 + r) * DIM + j * 256 + 4 * lane) = make_uint2(lo, hi);
    }
    #pragma unroll
    for (int e = 0; e < NE; ++e) {
      float4 w = wg4[e * 256 + j * 64 + lane];
      #pragma unroll
      for (int r = 0; r < 4; ++r)
        acc[r][e] += xv[r].x * w.x + xv[r].y * w.y + xv[r].z * w.z + xv[r].w * w.w;
    }
  }

  #pragma unroll
  for (int r = 0; r < 4; ++r) {
    int n = n0 + r;
    float v[NE];
    #pragma unroll
    for (int e = 0; e < NE; ++e) v[e] = acc[r][e];
    #pragma unroll
    for (int i = 0; i < 8; ++i) {
      float send = (lane & 32) ? v[i] : v[i + 8];
      float recv = __shfl_xor(send, 32, 64);
      v[i] = ((lane & 32) ? v[i + 8] : v[i]) + recv;
    }
    #pragma unroll
    for (int i = 0; i < 4; ++i) {
      float send = (lane & 16) ? v[i] : v[i + 4];
      float recv = __shfl_xor(send, 16, 64);
      v[i] = ((lane & 16) ? v[i + 4] : v[i]) + recv;
    }
    #pragma unroll
    for (int i = 0; i < 2; ++i) {
      float send = (lane & 8) ? v[i] : v[i + 2];
      float recv = __shfl_xor(send, 8, 64);
      v[i] = ((lane & 8) ? v[i + 2] : v[i]) + recv;
    }
    {
      float send = (lane & 4) ? v[0] : v[1];
      float recv = __shfl_xor(send, 4, 64);
      v[0] = ((lane & 4) ? v[1] : v[0]) + recv;
    }
    v[0] += __shfl_xor(v[0], 2, 64);
    v[0] += __shfl_xor(v[0], 1, 64);
    float lg = v[0];
    int e = ((lane >> 5) & 1) * 8 + ((lane >> 4) & 1) * 4 +
            ((lane >> 3) & 1) * 2 + ((lane >> 2) & 1);
    float m = lg;
    m = fmaxf(m, __shfl_xor(m, 4, 64));
    m = fmaxf(m, __shfl_xor(m, 8, 64));
    m = fmaxf(m, __shfl_xor(m, 16, 64));
    m = fmaxf(m, __shfl_xor(m, 32, 64));
    float p = expf(lg - m);
    float s = p;
    s += __shfl_xor(s, 4, 64);
    s += __shfl_xor(s, 8, 64);
    s += __shfl_xor(s, 16, 64);
    s += __shfl_xor(s, 32, 64);
    float inv = 1.f / s;
    if ((lane & 3) == 0) gate_out[(size_t)n * NE + e] = p * inv;
    unsigned long long msk = __ballot(lg == m);
    if (lane == 0) {
      int fl = __builtin_ctzll(msk);
      int ebest = ((fl >> 5) & 1) * 8 + ((fl >> 4) & 1) * 4 +
                  ((fl >> 3) & 1) * 2 + ((fl >> 2) & 1);
      eid[n] = ebest;
      wsel[n] = inv;
      atomicAdd(&hist[ebest], 1);
    }
  }
  __syncthreads();
  if (t < NE) hist_g[blockIdx.x * NE + t] = hist[t];
}

// ---------------- plan: reduce hists, prefix, tiles, cursors ----------------
__global__ __launch_bounds__(256) void plan_kernel(
    const int* __restrict__ hist_g, int* __restrict__ offsets,
    int* __restrict__ cursors, int4* __restrict__ tiles)
{
  __shared__ int part[16][17];
  __shared__ int sh_total;
  int t = threadIdx.x;
  int e = t & 15, chunk = t >> 4;
  int s = 0;
  #pragma unroll
  for (int i = 0; i < 32; ++i) s += hist_g[(chunk * 32 + i) * NE + e];
  part[chunk][e] = s;
  __syncthreads();
  if (t < 64) {
    int lane = t;
    int c = 0;
    if (lane < NE) {
      #pragma unroll
      for (int ch = 0; ch < 16; ++ch) c += part[ch][lane];
    }
    int nt = (c + BM - 1) >> 7;
    int po = c, pt = nt;
    #pragma unroll
    for (int d = 1; d < 16; d <<= 1) {
      int oc = __shfl_up(po, d, 64);
      int ot = __shfl_up(pt, d, 64);
      if (lane >= d) { po += oc; pt += ot; }
    }
    int off = po - c, tbase = pt - nt;
    if (lane < NE) { offsets[lane] = off; cursors[lane] = off; }
    if (lane == NE - 1) { offsets[NE] = po; sh_total = pt; }
    if (lane < NE) {
      int ti = 0;
      for (int m = 0; m < c; m += BM, ++ti)
        tiles[tbase + ti] = make_int4(lane, off + m, (c - m < BM) ? (c - m) : BM, 0);
    }
  }
  __syncthreads();
  for (int i = sh_total + t; i < MAXT; i += 256)
    tiles[i] = make_int4(-1, 0, 0, 0);
}

// ---------------- scatter rows by expert (cursors pre-seeded = offsets) ----
__global__ __launch_bounds__(256) void scatter_kernel(
    const int* __restrict__ eid, int* __restrict__ cursors,
    int* __restrict__ rowids)
{
  __shared__ int h[NE];
  __shared__ int base[NE];
  int t = threadIdx.x;
  if (t < NE) h[t] = 0;
  __syncthreads();
  int n = blockIdx.x * 256 + t;
  int e = eid[n];
  int local = atomicAdd(&h[e], 1);
  __syncthreads();
  if (t < NE) base[t] = h[t] ? atomicAdd(&cursors[t], h[t]) : 0;
  __syncthreads();
  rowids[base[e] + local] = n;
}

// ------- gathered per-expert GEMM, bf16, DEPTH-3 counted-vmcnt pipeline ----
// LDS per buffer: A 8KB (128 rows x 64B) + B 4KB (64 rows x 64B), 3 buffers.
// Slot swizzle: phys slot = cg ^ ((row>>1)&3); DMA dest linear, source
// pre-swizzled; ds_read applies same XOR -> 2-way max (free).
__global__ __launch_bounds__(256, 4) void moe_gemm_kernel(
    const ushort* __restrict__ xb, const ushort* __restrict__ Web,
    const float* __restrict__ be, const int* __restrict__ rowids,
    const float* __restrict__ wsel, const int4* __restrict__ tiles,
    float* __restrict__ out)
{
  __shared__ __align__(16) char lds[3 * 12288];   // 36 KB ring
  __shared__ int   rows_s[BM];
  __shared__ float w_s[BM];

  int4 ti = tiles[blockIdx.x];
  int e = ti.x;
  if (e < 0) return;
  int srow = ti.y, nvalid = ti.z;
  int t = threadIdx.x, lane = t & 63;
  int wid = t >> 6, wm = wid >> 1, wn = wid & 1;
  int ncol0 = blockIdx.y * BN;

  if (t < BM) {
    int valid = t < nvalid;
    int rid = valid ? rowids[srow + t] : 0;
    rows_s[t] = valid ? rid : -1;
    w_s[t] = valid ? wsel[rid] : 0.f;
  }

  // staging geometry: thread t -> A rows r1=t>>2, r1+64; B row r1; slot t&3
  int r1 = t >> 2, sl = t & 3;
  int r2 = r1 + 64;
  int cg = sl ^ ((r1 >> 1) & 3);
  int rida1 = (r1 < nvalid) ? rowids[srow + r1] : 0;
  int rida2 = (r2 < nvalid) ? rowids[srow + r2] : 0;
  const ushort* ap1 = xb + (size_t)rida1 * DIM + cg * 8;
  const ushort* ap2 = xb + (size_t)rida2 * DIM + cg * 8;
  const ushort* bp1 = Web + (size_t)e * OUTD * DIM + (size_t)(ncol0 + r1) * DIM + cg * 8;

  f32x4 zero = {0.f, 0.f, 0.f, 0.f};
  f32x4 acc[4][2];
  #pragma unroll
  for (int i = 0; i < 4; ++i)
    #pragma unroll
    for (int j = 0; j < 2; ++j) acc[i][j] = zero;

  auto stage = [&](int bufoff, int koff) {
    char* A = lds + bufoff;
    char* B = A + 8192;
    gload_lds16(ap1 + koff, A + t * 16);
    gload_lds16(ap2 + koff, A + 4096 + t * 16);
    gload_lds16(bp1 + koff, B + t * 16);
  };

  unsigned rl15 = lane & 15, rcg = lane >> 4;
  auto body = [&](int bufoff) {
    const char* A = lds + bufoff;
    const char* B = A + 8192;
    s16x8 af[4], bf_[2];
    #pragma unroll
    for (int f = 0; f < 4; ++f) {
      unsigned rA = wm * 64 + f * 16 + rl15;
      af[f] = *(const s16x8*)(A + rA * 64 + ((rcg ^ ((rA >> 1) & 3)) * 16));
    }
    #pragma unroll
    for (int f = 0; f < 2; ++f) {
      unsigned rB = wn * 32 + f * 16 + rl15;
      bf_[f] = *(const s16x8*)(B + rB * 64 + ((rcg ^ ((rB >> 1) & 3)) * 16));
    }
    #pragma unroll
    for (int fm = 0; fm < 4; ++fm)
      #pragma unroll
      for (int fn = 0; fn < 2; ++fn)
        acc[fm][fn] = __builtin_amdgcn_mfma_f32_16x16x32_bf16(af[fm], bf_[fn], acc[fm][fn], 0, 0, 0);
  };

  // drain setup loads so vmcnt accounting below is exact
  asm volatile("s_waitcnt vmcnt(0)" ::: "memory");
  stage(0, 0);
  stage(12288, BK);
  int stg = 24576, cur = 0;

  for (int ks = 0; ks < NKSTEP - 1; ++ks) {
    asm volatile("s_waitcnt vmcnt(3)" ::: "memory");   // cur buffer's 3 DMAs done
    __builtin_amdgcn_s_barrier();                      // all waves' DMAs done,
    asm volatile("" ::: "memory");                     // prior readers finished
    if (ks < NKSTEP - 2) {
      stage(stg, (ks + 2) * BK);
      stg = (stg == 24576) ? 0 : stg + 12288;
    }
    body(cur);
    cur = (cur == 24576) ? 0 : cur + 12288;
  }
  asm volatile("s_waitcnt vmcnt(0)" ::: "memory");
  __builtin_amdgcn_s_barrier();
  asm volatile("" ::: "memory");
  body(cur);

  // epilogue: out[row][col] = w * (acc + be[e][col])
  int rgrp = lane >> 4;
  #pragma unroll
  for (int fn = 0; fn < 2; ++fn) {
    int col = ncol0 + wn * 32 + fn * 16 + (lane & 15);
    float bev = be[e * OUTD + col];
    #pragma unroll
    for (int fm = 0; fm < 4; ++fm) {
      #pragma unroll
      for (int j = 0; j < 4; ++j) {
        int rl = wm * 64 + fm * 16 + rgrp * 4 + j;
        int orow = rows_s[rl];
        if (orow >= 0) {
          float w = w_s[rl];
          out[(size_t)orow * OUTD + col] = w * (acc[fm][fn][j] + bev);
        }
      }
    }
  }
}

extern "C" void kernel_launch(void* const* d_in, const int* in_sizes, int n_in,
                              void* d_out, int out_size, void* d_ws, size_t ws_size,
                              hipStream_t stream) {
  const float* x  = (const float*)d_in[0];
  const float* Wg = (const float*)d_in[1];
  const float* We = (const float*)d_in[2];
  const float* be = (const float*)d_in[3];
  float* out = (float*)d_out;
  float* gate_out = out + (size_t)NROWS * OUTD;

  char* ws = (char*)d_ws;
  int*  cursors = (int*)ws;                        // 16 @ 0
  int*  offsets = (int*)(ws + 64);                 // 17 @ 64
  int4* tiles   = (int4*)(ws + 256);               // 96*16 B
  int*  hist_g  = (int*)(ws + 4096);               // 512*16*4 = 32 KB
  int*  eidp    = (int*)(ws + 40960);              // 32 KB
  float* wselp  = (float*)(ws + 40960 + 4 * NROWS);
  int*  rowids  = (int*)(ws + 40960 + 8 * NROWS);
  ushort* xb    = (ushort*)(ws + (1u << 20));                  // 16 MB
  ushort* Web   = (ushort*)(ws + (1u << 20) + 16777216u);      // 32 MB

  hipLaunchKernelGGL(convert_we_kernel, dim3(CONVBLKS), dim3(256), 0, stream, We, Web);
  hipLaunchKernelGGL(gate_kernel, dim3(GATEBLKS), dim3(256), 0, stream,
                     x, Wg, gate_out, eidp, wselp, xb, hist_g);
  hipLaunchKernelGGL(plan_kernel, dim3(1), dim3(256), 0, stream,
                     hist_g, offsets, cursors, tiles);
  hipLaunchKernelGGL(scatter_kernel, dim3(NROWS / 256), dim3(256), 0, stream,
                     eidp, cursors, rowids);
  hipLaunchKernelGGL(moe_gemm_kernel, dim3(MAXT, NTILE), dim3(256), 0, stream,
                     xb, Web, be, rowids, wselp, tiles, out);
}

// Round 7
// 212.434 us; speedup vs baseline: 1.0904x; 1.0896x over previous
//
#include <hip/hip_runtime.h>
#include <hip/hip_bf16.h>

#define NROWS 8192
#define DIM   1024
#define OUTD  1024
#define NE    16
#define BM    128
#define BN    128
#define BK    32
#define MAXT  96
#define NKSTEP (DIM / BK)   // 32
#define NCOL   (OUTD / BN)  // 8
#define GATEBLKS 512
#define CONVBLKS 2048

typedef short s16x8 __attribute__((ext_vector_type(8)));
typedef float f32x16 __attribute__((ext_vector_type(16)));

__device__ __forceinline__ unsigned f2bf(float f) {
  __hip_bfloat16 h = __float2bfloat16(f);
  return (unsigned)__builtin_bit_cast(unsigned short, h);
}

__device__ __forceinline__ void gload_lds16(const void* g, void* l) {
  __builtin_amdgcn_global_load_lds(
      (const __attribute__((address_space(1))) void*)g,
      (__attribute__((address_space(3))) void*)l, 16, 0, 0);
}

// ---------------- We fp32 -> bf16 (no LDS, full occupancy) ----------------
__global__ __launch_bounds__(256) void convert_we_kernel(
    const float* __restrict__ W, ushort* __restrict__ o) {
  size_t base = ((size_t)blockIdx.x * 256 + threadIdx.x) * 8;
  #pragma unroll
  for (int i = 0; i < 4; ++i) {
    size_t idx = base + (size_t)i * ((size_t)CONVBLKS * 256 * 8);
    float4 a = *(const float4*)(W + idx);
    float4 c = *(const float4*)(W + idx + 4);
    unsigned w0 = f2bf(a.x) | (f2bf(a.y) << 16);
    unsigned w1 = f2bf(a.z) | (f2bf(a.w) << 16);
    unsigned w2 = f2bf(c.x) | (f2bf(c.y) << 16);
    unsigned w3 = f2bf(c.z) | (f2bf(c.w) << 16);
    *(uint4*)(o + idx) = make_uint4(w0, w1, w2, w3);
  }
}

// ------- gate: full-D fp32 logits (Wg in 64KB LDS), butterfly reduce,
// ------- softmax, argmax, fused x->bf16 conversion, per-block histogram ----
__global__ __launch_bounds__(256) void gate_kernel(
    const float* __restrict__ x, const float* __restrict__ Wg,
    float* __restrict__ gate_out, int* __restrict__ eid,
    float* __restrict__ wsel, ushort* __restrict__ xb,
    int* __restrict__ hist_g)
{
  __shared__ __align__(16) float4 wg4[NE * 256];  // 64 KB fp32 Wg
  __shared__ int hist[NE];
  int t = threadIdx.x;
  int wid = t >> 6, lane = t & 63;
  if (t < NE) hist[t] = 0;
  const float4* wgg = (const float4*)Wg;
  #pragma unroll
  for (int i = 0; i < 16; ++i) wg4[t + i * 256] = wgg[t + i * 256];
  __syncthreads();

  int n0 = blockIdx.x * 16 + wid * 4;

  float acc[4][NE];
  #pragma unroll
  for (int r = 0; r < 4; ++r)
    #pragma unroll
    for (int e = 0; e < NE; ++e) acc[r][e] = 0.f;

  #pragma unroll
  for (int j = 0; j < 4; ++j) {
    float4 xv[4];
    #pragma unroll
    for (int r = 0; r < 4; ++r) {
      xv[r] = *(const float4*)(x + (size_t)(n0 + r) * DIM + j * 256 + 4 * lane);
      unsigned lo = f2bf(xv[r].x) | (f2bf(xv[r].y) << 16);
      unsigned hi = f2bf(xv[r].z) | (f2bf(xv[r].w) << 16);
      *(uint2*)(xb + (size_t)(n0 + r) * DIM + j * 256 + 4 * lane) = make_uint2(lo, hi);
    }
    #pragma unroll
    for (int e = 0; e < NE; ++e) {
      float4 w = wg4[e * 256 + j * 64 + lane];
      #pragma unroll
      for (int r = 0; r < 4; ++r)
        acc[r][e] += xv[r].x * w.x + xv[r].y * w.y + xv[r].z * w.z + xv[r].w * w.w;
    }
  }

  #pragma unroll
  for (int r = 0; r < 4; ++r) {
    int n = n0 + r;
    float v[NE];
    #pragma unroll
    for (int e = 0; e < NE; ++e) v[e] = acc[r][e];
    #pragma unroll
    for (int i = 0; i < 8; ++i) {
      float send = (lane & 32) ? v[i] : v[i + 8];
      float recv = __shfl_xor(send, 32, 64);
      v[i] = ((lane & 32) ? v[i + 8] : v[i]) + recv;
    }
    #pragma unroll
    for (int i = 0; i < 4; ++i) {
      float send = (lane & 16) ? v[i] : v[i + 4];
      float recv = __shfl_xor(send, 16, 64);
      v[i] = ((lane & 16) ? v[i + 4] : v[i]) + recv;
    }
    #pragma unroll
    for (int i = 0; i < 2; ++i) {
      float send = (lane & 8) ? v[i] : v[i + 2];
      float recv = __shfl_xor(send, 8, 64);
      v[i] = ((lane & 8) ? v[i + 2] : v[i]) + recv;
    }
    {
      float send = (lane & 4) ? v[0] : v[1];
      float recv = __shfl_xor(send, 4, 64);
      v[0] = ((lane & 4) ? v[1] : v[0]) + recv;
    }
    v[0] += __shfl_xor(v[0], 2, 64);
    v[0] += __shfl_xor(v[0], 1, 64);
    float lg = v[0];
    int e = ((lane >> 5) & 1) * 8 + ((lane >> 4) & 1) * 4 +
            ((lane >> 3) & 1) * 2 + ((lane >> 2) & 1);
    float m = lg;
    m = fmaxf(m, __shfl_xor(m, 4, 64));
    m = fmaxf(m, __shfl_xor(m, 8, 64));
    m = fmaxf(m, __shfl_xor(m, 16, 64));
    m = fmaxf(m, __shfl_xor(m, 32, 64));
    float p = expf(lg - m);
    float s = p;
    s += __shfl_xor(s, 4, 64);
    s += __shfl_xor(s, 8, 64);
    s += __shfl_xor(s, 16, 64);
    s += __shfl_xor(s, 32, 64);
    float inv = 1.f / s;
    if ((lane & 3) == 0) gate_out[(size_t)n * NE + e] = p * inv;
    unsigned long long msk = __ballot(lg == m);
    if (lane == 0) {
      int fl = __builtin_ctzll(msk);
      int ebest = ((fl >> 5) & 1) * 8 + ((fl >> 4) & 1) * 4 +
                  ((fl >> 3) & 1) * 2 + ((fl >> 2) & 1);
      eid[n] = ebest;
      wsel[n] = inv;
      atomicAdd(&hist[ebest], 1);
    }
  }
  __syncthreads();
  if (t < NE) hist_g[blockIdx.x * NE + t] = hist[t];
}

// ---------------- plan: reduce hists, prefix, tiles, cursors ----------------
__global__ __launch_bounds__(256) void plan_kernel(
    const int* __restrict__ hist_g, int* __restrict__ offsets,
    int* __restrict__ cursors, int4* __restrict__ tiles)
{
  __shared__ int part[16][17];
  __shared__ int sh_total;
  int t = threadIdx.x;
  int e = t & 15, chunk = t >> 4;
  int s = 0;
  #pragma unroll
  for (int i = 0; i < 32; ++i) s += hist_g[(chunk * 32 + i) * NE + e];
  part[chunk][e] = s;
  __syncthreads();
  if (t < 64) {
    int lane = t;
    int c = 0;
    if (lane < NE) {
      #pragma unroll
      for (int ch = 0; ch < 16; ++ch) c += part[ch][lane];
    }
    int nt = (c + BM - 1) >> 7;
    int po = c, pt = nt;
    #pragma unroll
    for (int d = 1; d < 16; d <<= 1) {
      int oc = __shfl_up(po, d, 64);
      int ot = __shfl_up(pt, d, 64);
      if (lane >= d) { po += oc; pt += ot; }
    }
    int off = po - c, tbase = pt - nt;
    if (lane < NE) { offsets[lane] = off; cursors[lane] = off; }
    if (lane == NE - 1) { offsets[NE] = po; sh_total = pt; }
    if (lane < NE) {
      int ti = 0;
      for (int m = 0; m < c; m += BM, ++ti)
        tiles[tbase + ti] = make_int4(lane, off + m, (c - m < BM) ? (c - m) : BM, 0);
    }
  }
  __syncthreads();
  for (int i = sh_total + t; i < MAXT; i += 256)
    tiles[i] = make_int4(-1, 0, 0, 0);
}

// ---------------- scatter rows by expert (cursors pre-seeded = offsets) ----
__global__ __launch_bounds__(256) void scatter_kernel(
    const int* __restrict__ eid, int* __restrict__ cursors,
    int* __restrict__ rowids)
{
  __shared__ int h[NE];
  __shared__ int base[NE];
  int t = threadIdx.x;
  if (t < NE) h[t] = 0;
  __syncthreads();
  int n = blockIdx.x * 256 + t;
  int e = eid[n];
  int local = atomicAdd(&h[e], 1);
  __syncthreads();
  if (t < NE) base[t] = h[t] ? atomicAdd(&cursors[t], h[t]) : 0;
  __syncthreads();
  rowids[base[e] + local] = n;
}

// ------- gathered per-expert GEMM, bf16, 32x32x16 MFMA, m97 2-barrier ------
// Grid: 1-D, 768 blocks; col = bid&7 (-> XCD partition: each XCD owns one
// 128-col panel; its B set = 16 experts x 256KB = 4MB = L2), rowtile = bid>>3.
// LDS per buffer: A 8KB (128 rows x 64B) + B 8KB; double buffered = 32KB.
// Slot swizzle: phys 16B-slot = logical ^ ((row>>1)&3); DMA dest linear,
// source pre-swizzled; ds_read applies same XOR -> 2-way max (free).
__global__ __launch_bounds__(256, 4) void moe_gemm_kernel(
    const ushort* __restrict__ xb, const ushort* __restrict__ Web,
    const float* __restrict__ be, const int* __restrict__ rowids,
    const float* __restrict__ wsel, const int4* __restrict__ tiles,
    float* __restrict__ out)
{
  __shared__ __align__(16) char lds[2 * 16384];   // A0 B0 | A1 B1
  __shared__ int   rows_s[BM];
  __shared__ float w_s[BM];

  int rt = blockIdx.x >> 3, c = blockIdx.x & 7;
  int4 ti = tiles[rt];
  int e = ti.x;
  if (e < 0) return;
  int srow = ti.y, nvalid = ti.z;
  int t = threadIdx.x, lane = t & 63;
  int wid = t >> 6, wm = wid >> 1, wn = wid & 1;
  int ncol0 = c * BN;

  if (t < BM) {
    int valid = t < nvalid;
    int rid = valid ? rowids[srow + t] : 0;
    rows_s[t] = valid ? rid : -1;
    w_s[t] = valid ? wsel[rid] : 0.f;
  }

  // staging geometry: thread t -> rows r1=t>>2, r1+64 (A and B); slot t&3
  int r1 = t >> 2, sl = t & 3;
  int r2 = r1 + 64;
  int cg = sl ^ ((r1 >> 1) & 3);     // ((r1+64)>>1)&3 == (r1>>1)&3
  int rida1 = (r1 < nvalid) ? rowids[srow + r1] : 0;
  int rida2 = (r2 < nvalid) ? rowids[srow + r2] : 0;
  const ushort* ap1 = xb + (size_t)rida1 * DIM + cg * 8;
  const ushort* ap2 = xb + (size_t)rida2 * DIM + cg * 8;
  const ushort* bb  = Web + (size_t)e * OUTD * DIM + (size_t)ncol0 * DIM + cg * 8;
  const ushort* bp1 = bb + (size_t)r1 * DIM;
  const ushort* bp2 = bb + (size_t)r2 * DIM;

  f32x16 acc[2][2];
  #pragma unroll
  for (int i = 0; i < 2; ++i)
    #pragma unroll
    for (int j = 0; j < 2; ++j)
      #pragma unroll
      for (int r = 0; r < 16; ++r) acc[i][j][r] = 0.f;

  auto stage = [&](int bufoff, int koff) {
    char* A = lds + bufoff;
    char* B = A + 8192;
    gload_lds16(ap1 + koff, A + t * 16);
    gload_lds16(ap2 + koff, A + 4096 + t * 16);
    gload_lds16(bp1 + koff, B + t * 16);
    gload_lds16(bp2 + koff, B + 4096 + t * 16);
  };

  unsigned l31 = lane & 31, lhi = lane >> 5;
  auto body = [&](int bufoff) {
    const char* A = lds + bufoff;
    const char* B = A + 8192;
    s16x8 af[2][2], bfr[2][2];
    #pragma unroll
    for (int rb = 0; rb < 2; ++rb)
      #pragma unroll
      for (int ku = 0; ku < 2; ++ku) {
        unsigned rA = wm * 64 + rb * 32 + l31;
        unsigned slA = (unsigned)(ku * 2 + lhi) ^ ((rA >> 1) & 3);
        af[rb][ku] = *(const s16x8*)(A + rA * 64 + slA * 16);
        unsigned rB = wn * 64 + rb * 32 + l31;
        unsigned slB = (unsigned)(ku * 2 + lhi) ^ ((rB >> 1) & 3);
        bfr[rb][ku] = *(const s16x8*)(B + rB * 64 + slB * 16);
      }
    #pragma unroll
    for (int ku = 0; ku < 2; ++ku)
      #pragma unroll
      for (int rb = 0; rb < 2; ++rb)
        #pragma unroll
        for (int cb = 0; cb < 2; ++cb)
          acc[rb][cb] = __builtin_amdgcn_mfma_f32_32x32x16_bf16(
              af[rb][ku], bfr[cb][ku], acc[rb][cb], 0, 0, 0);
  };

  stage(0, 0);
  for (int ks = 0; ks < NKSTEP; ++ks) {
    __syncthreads();   // drains vmcnt: cur buffer staged; prev reads done
    if (ks + 1 < NKSTEP) stage(((ks + 1) & 1) * 16384, (ks + 1) * BK);
    body((ks & 1) * 16384);
  }

  // epilogue: out[row][col] = w * (acc + be[e][col])
  // C/D layout (32x32): col = lane&31, row = (reg&3) + 8*(reg>>2) + 4*(lane>>5)
  #pragma unroll
  for (int cb = 0; cb < 2; ++cb) {
    int col = ncol0 + wn * 64 + cb * 32 + l31;
    float bev = be[e * OUTD + col];
    #pragma unroll
    for (int rb = 0; rb < 2; ++rb) {
      #pragma unroll
      for (int r = 0; r < 16; ++r) {
        int rowin = (r & 3) + 8 * (r >> 2) + 4 * lhi;
        int rl = wm * 64 + rb * 32 + rowin;
        int orow = rows_s[rl];
        if (orow >= 0)
          out[(size_t)orow * OUTD + col] = w_s[rl] * (acc[rb][cb][r] + bev);
      }
    }
  }
}

extern "C" void kernel_launch(void* const* d_in, const int* in_sizes, int n_in,
                              void* d_out, int out_size, void* d_ws, size_t ws_size,
                              hipStream_t stream) {
  const float* x  = (const float*)d_in[0];
  const float* Wg = (const float*)d_in[1];
  const float* We = (const float*)d_in[2];
  const float* be = (const float*)d_in[3];
  float* out = (float*)d_out;
  float* gate_out = out + (size_t)NROWS * OUTD;

  char* ws = (char*)d_ws;
  int*  cursors = (int*)ws;                        // 16 @ 0
  int*  offsets = (int*)(ws + 64);                 // 17 @ 64
  int4* tiles   = (int4*)(ws + 256);               // 96*16 B
  int*  hist_g  = (int*)(ws + 4096);               // 512*16*4 = 32 KB
  int*  eidp    = (int*)(ws + 40960);              // 32 KB
  float* wselp  = (float*)(ws + 40960 + 4 * NROWS);
  int*  rowids  = (int*)(ws + 40960 + 8 * NROWS);
  ushort* xb    = (ushort*)(ws + (1u << 20));                  // 16 MB
  ushort* Web   = (ushort*)(ws + (1u << 20) + 16777216u);      // 32 MB

  hipLaunchKernelGGL(convert_we_kernel, dim3(CONVBLKS), dim3(256), 0, stream, We, Web);
  hipLaunchKernelGGL(gate_kernel, dim3(GATEBLKS), dim3(256), 0, stream,
                     x, Wg, gate_out, eidp, wselp, xb, hist_g);
  hipLaunchKernelGGL(plan_kernel, dim3(1), dim3(256), 0, stream,
                     hist_g, offsets, cursors, tiles);
  hipLaunchKernelGGL(scatter_kernel, dim3(NROWS / 256), dim3(256), 0, stream,
                     eidp, cursors, rowids);
  hipLaunchKernelGGL(moe_gemm_kernel, dim3(MAXT * 8), dim3(256), 0, stream,
                     xb, Web, be, rowids, wselp, tiles, out);
}